// Round 1
// baseline (161.987 us; speedup 1.0000x reference)
//
#include <hip/hip_runtime.h>
#include <math.h>

// Gumbel subset (relaxed top-k) — B=2048 rows, N=8192, K=64 softmax steps.
// Reformulated multiplicatively: v_i = exp(s0_i - M0) carried in registers,
// per step: p = v/sum(v); khot += p; v *= max(1-p, EPS).
// Algebraically identical to reference (TAU=1), zero transcendentals in loop.

#define BROWS 2048
#define NCOLS 8192
#define KSTEPS 64
#define EPSV 1e-10f

#define THREADS 256
#define EPT (NCOLS / THREADS) // 32 elements per thread, held in registers

__global__ __launch_bounds__(THREADS) void gumbel_subset_kernel(
    const float* __restrict__ scores,
    const float* __restrict__ g,
    float* __restrict__ out)
{
    const int row = blockIdx.x;
    const int t = threadIdx.x;
    const float* __restrict__ srow = scores + (size_t)row * NCOLS;
    const float* __restrict__ grow = g + (size_t)row * NCOLS;
    float* __restrict__ orow = out + (size_t)row * NCOLS;

    float v[EPT];
    float kh[EPT];

    // ---- load s0 = scores + g (coalesced float4), track local max ----
    float m = -INFINITY;
#pragma unroll
    for (int c = 0; c < EPT / 4; ++c) {
        const int idx = c * (THREADS * 4) + t * 4;
        const float4 a = *reinterpret_cast<const float4*>(srow + idx);
        const float4 b = *reinterpret_cast<const float4*>(grow + idx);
        const float s0 = a.x + b.x;
        const float s1 = a.y + b.y;
        const float s2 = a.z + b.z;
        const float s3 = a.w + b.w;
        v[c * 4 + 0] = s0;
        v[c * 4 + 1] = s1;
        v[c * 4 + 2] = s2;
        v[c * 4 + 3] = s3;
        m = fmaxf(m, fmaxf(fmaxf(s0, s1), fmaxf(s2, s3)));
    }

    __shared__ float red[2][8]; // double-buffered per-wave partials (4 waves used)
    const int wave = t >> 6;
    const int lane = t & 63;

    // ---- block max reduction (once) ----
#pragma unroll
    for (int off = 32; off > 0; off >>= 1)
        m = fmaxf(m, __shfl_xor(m, off, 64));
    if (lane == 0) red[0][wave] = m;
    __syncthreads();
    m = fmaxf(fmaxf(red[0][0], red[0][1]), fmaxf(red[0][2], red[0][3]));
    __syncthreads(); // red[0] is re-written by iteration 0 below

    // ---- v = exp(s0 - M0), khot = 0 ----
#pragma unroll
    for (int e = 0; e < EPT; ++e) {
        v[e] = __expf(v[e] - m);
        kh[e] = 0.0f;
    }

    // ---- K relaxation steps ----
    for (int it = 0; it < KSTEPS; ++it) {
        float s = 0.0f;
#pragma unroll
        for (int e = 0; e < EPT; ++e) s += v[e];
#pragma unroll
        for (int off = 32; off > 0; off >>= 1)
            s += __shfl_xor(s, off, 64);

        const int buf = it & 1;
        if (lane == 0) red[buf][wave] = s;
        __syncthreads();
        const float S = (red[buf][0] + red[buf][1]) + (red[buf][2] + red[buf][3]);
        const float rinv = 1.0f / S;

#pragma unroll
        for (int e = 0; e < EPT; ++e) {
            const float p = v[e] * rinv;
            kh[e] += p;
            v[e] *= fmaxf(1.0f - p, EPSV);
        }
        // double-buffered red[] -> single barrier per iteration is safe:
        // next write targets the other buffer; the buffer just read is only
        // re-written after the *next* barrier.
    }

    // ---- store khot (coalesced float4) ----
#pragma unroll
    for (int c = 0; c < EPT / 4; ++c) {
        const int idx = c * (THREADS * 4) + t * 4;
        float4 o;
        o.x = kh[c * 4 + 0];
        o.y = kh[c * 4 + 1];
        o.z = kh[c * 4 + 2];
        o.w = kh[c * 4 + 3];
        *reinterpret_cast<float4*>(orow + idx) = o;
    }
}

extern "C" void kernel_launch(void* const* d_in, const int* in_sizes, int n_in,
                              void* d_out, int out_size, void* d_ws, size_t ws_size,
                              hipStream_t stream) {
    const float* scores = (const float*)d_in[0];
    const float* g = (const float*)d_in[1];
    float* out = (float*)d_out;
    (void)in_sizes; (void)n_in; (void)out_size; (void)d_ws; (void)ws_size;

    gumbel_subset_kernel<<<BROWS, THREADS, 0, stream>>>(scores, g, out);
}

// Round 2
// 110.641 us; speedup vs baseline: 1.4641x; 1.4641x over previous
//
#include <hip/hip_runtime.h>
#include <math.h>

// Gumbel subset (relaxed top-k) — B=2048 rows, N=8192, K=64 softmax steps.
// Multiplicative reformulation: v_i = exp(s0_i - M0) carried in registers.
// Per step: w = v*rinv(S); kh += w; v = fma(-w, v, v)  [= v*(1-p)].
// EPS clamp dropped (only reachable at p >= 1-1e-10; impossible at N=8192,
// and the rounding corner degrades to v~0 which matches ref within 1e-9).

#define BROWS 2048
#define NCOLS 8192
#define KSTEPS 64

#define THREADS 256
#define EPT (NCOLS / THREADS) // 32 elements per thread, held in registers

__global__ __launch_bounds__(THREADS, 4) void gumbel_subset_kernel(
    const float* __restrict__ scores,
    const float* __restrict__ g,
    float* __restrict__ out)
{
    const int row = blockIdx.x;
    const int t = threadIdx.x;
    const float* __restrict__ srow = scores + (size_t)row * NCOLS;
    const float* __restrict__ grow = g + (size_t)row * NCOLS;
    float* __restrict__ orow = out + (size_t)row * NCOLS;

    float v[EPT];
    float kh[EPT];

    // ---- load s0 = scores + g (coalesced float4), track local max ----
    float m = -INFINITY;
#pragma unroll
    for (int c = 0; c < EPT / 4; ++c) {
        const int idx = c * (THREADS * 4) + t * 4;
        const float4 a = *reinterpret_cast<const float4*>(srow + idx);
        const float4 b = *reinterpret_cast<const float4*>(grow + idx);
        const float s0 = a.x + b.x;
        const float s1 = a.y + b.y;
        const float s2 = a.z + b.z;
        const float s3 = a.w + b.w;
        v[c * 4 + 0] = s0;
        v[c * 4 + 1] = s1;
        v[c * 4 + 2] = s2;
        v[c * 4 + 3] = s3;
        m = fmaxf(m, fmaxf(fmaxf(s0, s1), fmaxf(s2, s3)));
    }

    __shared__ float red[2][8]; // double-buffered per-wave partials (4 waves used)
    const int wave = t >> 6;
    const int lane = t & 63;

    // ---- block max reduction (once) ----
#pragma unroll
    for (int off = 32; off > 0; off >>= 1)
        m = fmaxf(m, __shfl_xor(m, off, 64));
    if (lane == 0) red[0][wave] = m;
    __syncthreads();
    m = fmaxf(fmaxf(red[0][0], red[0][1]), fmaxf(red[0][2], red[0][3]));
    __syncthreads(); // red[0] is re-written by iteration 0 below

    // ---- v = exp(s0 - M0), khot = 0 ----
#pragma unroll
    for (int e = 0; e < EPT; ++e) {
        v[e] = __expf(v[e] - m);
        kh[e] = 0.0f;
    }

    // ---- K relaxation steps ----
#pragma unroll 2
    for (int it = 0; it < KSTEPS; ++it) {
        float s = 0.0f;
#pragma unroll
        for (int e = 0; e < EPT; ++e) s += v[e];
#pragma unroll
        for (int off = 32; off > 0; off >>= 1)
            s += __shfl_xor(s, off, 64);

        const int buf = it & 1;
        if (lane == 0) red[buf][wave] = s;
        __syncthreads();
        const float S = (red[buf][0] + red[buf][1]) + (red[buf][2] + red[buf][3]);
        const float rinv = __builtin_amdgcn_rcpf(S);

#pragma unroll
        for (int e = 0; e < EPT; ++e) {
            const float w = v[e] * rinv;        // p_i
            kh[e] += w;
            v[e] = __builtin_fmaf(-w, v[e], v[e]); // v *= (1 - p)
        }
        // double-buffered red[] -> single barrier per iteration is safe:
        // next write targets the other buffer; the buffer just read is only
        // re-written after the *next* barrier.
    }

    // ---- store khot (coalesced float4) ----
#pragma unroll
    for (int c = 0; c < EPT / 4; ++c) {
        const int idx = c * (THREADS * 4) + t * 4;
        float4 o;
        o.x = kh[c * 4 + 0];
        o.y = kh[c * 4 + 1];
        o.z = kh[c * 4 + 2];
        o.w = kh[c * 4 + 3];
        *reinterpret_cast<float4*>(orow + idx) = o;
    }
}

extern "C" void kernel_launch(void* const* d_in, const int* in_sizes, int n_in,
                              void* d_out, int out_size, void* d_ws, size_t ws_size,
                              hipStream_t stream) {
    const float* scores = (const float*)d_in[0];
    const float* g = (const float*)d_in[1];
    float* out = (float*)d_out;
    (void)in_sizes; (void)n_in; (void)out_size; (void)d_ws; (void)ws_size;

    gumbel_subset_kernel<<<BROWS, THREADS, 0, stream>>>(scores, g, out);
}